// Round 8
// baseline (188.421 us; speedup 1.0000x reference)
//
#include <hip/hip_runtime.h>

typedef __bf16 bf16_t;
typedef __bf16 bf16x8 __attribute__((ext_vector_type(8)));
typedef __bf16 bf16x4v __attribute__((ext_vector_type(4)));
typedef __bf16 bf16x2 __attribute__((ext_vector_type(2)));
typedef float f32x4 __attribute__((ext_vector_type(4)));

__device__ __forceinline__ float tanh_fast(float x) {
  float a = fabsf(x);
  float e = __expf(-2.f * a);
  float t = (1.f - e) * __builtin_amdgcn_rcpf(1.f + e);
  return copysignf(t, x);
}

__device__ __forceinline__ void gload16(const void* g, void* l) {
  __builtin_amdgcn_global_load_lds(
      (const __attribute__((address_space(1))) void*)g,
      (__attribute__((address_space(3))) void*)l, 16, 0, 0);
}

// ------- fast path: cast W -> bf16 + pre-layout conv2 weights (x handled in GEMM1)
__global__ __launch_bounds__(256) void cast_w_k(const float* __restrict__ Ww,
                                                const float* __restrict__ w2,
                                                bf16_t* __restrict__ Wbf,
                                                bf16_t* __restrict__ w2rg) {
  const int bid = blockIdx.x;
  const int tid = threadIdx.x;
  if (bid < 512) {
    const int i = bid * 256 + tid;
    float4 v = ((const float4*)Ww)[i];
    bf16x4v o;
    o[0] = (bf16_t)v.x; o[1] = (bf16_t)v.y; o[2] = (bf16_t)v.z; o[3] = (bf16_t)v.w;
    ((bf16x4v*)Wbf)[i] = o;
  } else {
    for (int i = tid; i < 3072; i += 256) {
      int o = i / 96, rem = i % 96, c = rem / 3, kk = rem % 3;
      w2rg[kk * 1024 + o * 32 + c] = (bf16_t)w2[i];
    }
  }
}

// ------- fallback: cast x + W + conv2 weights (round-1 structure needs xb)
__global__ __launch_bounds__(256) void cast_all_k(const float* __restrict__ x,
                                                  const float* __restrict__ Ww,
                                                  const float* __restrict__ w2,
                                                  bf16_t* __restrict__ xb,
                                                  bf16_t* __restrict__ Wbf,
                                                  bf16_t* __restrict__ w2rg) {
  const int bid = blockIdx.x;
  const int tid = threadIdx.x;
  if (bid < 4096) {
    const int i = bid * 256 + tid;
    float4 v = ((const float4*)x)[i];
    bf16x4v o;
    o[0] = (bf16_t)v.x; o[1] = (bf16_t)v.y; o[2] = (bf16_t)v.z; o[3] = (bf16_t)v.w;
    ((bf16x4v*)xb)[i] = o;
  } else if (bid < 4608) {
    const int i = (bid - 4096) * 256 + tid;
    float4 v = ((const float4*)Ww)[i];
    bf16x4v o;
    o[0] = (bf16_t)v.x; o[1] = (bf16_t)v.y; o[2] = (bf16_t)v.z; o[3] = (bf16_t)v.w;
    ((bf16x4v*)Wbf)[i] = o;
  } else {
    for (int i = tid; i < 3072; i += 256) {
      int o = i / 96, rem = i % 96, c = rem / 3, kk = rem % 3;
      w2rg[kk * 1024 + o * 32 + c] = (bf16_t)w2[i];
    }
  }
}

// ===== fused GEMM1: h = x@W^T + b (x cast inline), writes h AND hT =====
__global__ __launch_bounds__(256) void gemm1_fused_k(const float* __restrict__ x,
                                                     const bf16_t* __restrict__ Wbf,
                                                     const float* __restrict__ bias,
                                                     bf16_t* __restrict__ h,
                                                     bf16_t* __restrict__ hT) {
  __shared__ bf16_t As[64 * 32];
  __shared__ bf16_t Bs[128 * 32];
  __shared__ bf16_t tileO[64][136];  // padded rows (16B-aligned, bank-shifted)
  const int tid = threadIdx.x;
  const int w = tid >> 6, l = tid & 63;
  const int lr = l & 15, lkq = l >> 4;
  const int bx = blockIdx.x, by = blockIdx.y;

  const float* Ax   = x + (size_t)(by * 64 + (tid >> 2)) * 1024 + (tid & 3) * 8;
  const bf16_t* Bg0 = Wbf + (size_t)(bx * 128 + (tid >> 2)) * 1024 + (tid & 3) * 8;
  const bf16_t* Bg1 = Bg0 + (size_t)64 * 1024;
  bf16_t* lA  = As + tid * 8;
  bf16_t* lB0 = Bs + tid * 8;
  bf16_t* lB1 = Bs + 2048 + tid * 8;

  f32x4 acc[4][2];
#pragma unroll
  for (int m = 0; m < 4; ++m)
#pragma unroll
    for (int n = 0; n < 2; ++n) acc[m][n] = (f32x4){0.f, 0.f, 0.f, 0.f};

  for (int kt = 0; kt < 1024; kt += 32) {
    float4 xa = *(const float4*)(Ax + kt);
    float4 xc = *(const float4*)(Ax + kt + 4);
    gload16(Bg0 + kt, lB0);
    gload16(Bg1 + kt, lB1);
    bf16x8 av;
    av[0] = (bf16_t)xa.x; av[1] = (bf16_t)xa.y; av[2] = (bf16_t)xa.z; av[3] = (bf16_t)xa.w;
    av[4] = (bf16_t)xc.x; av[5] = (bf16_t)xc.y; av[6] = (bf16_t)xc.z; av[7] = (bf16_t)xc.w;
    *(bf16x8*)lA = av;
    __syncthreads();  // drains vmcnt+lgkmcnt
    bf16x8 af[4], bfv[2];
#pragma unroll
    for (int m = 0; m < 4; ++m)
      af[m] = *(const bf16x8*)&As[(m * 16 + lr) * 32 + lkq * 8];
#pragma unroll
    for (int n = 0; n < 2; ++n)
      bfv[n] = *(const bf16x8*)&Bs[(w * 32 + n * 16 + lr) * 32 + lkq * 8];
#pragma unroll
    for (int m = 0; m < 4; ++m)
#pragma unroll
      for (int n = 0; n < 2; ++n)
        acc[m][n] = __builtin_amdgcn_mfma_f32_16x16x32_bf16(af[m], bfv[n], acc[m][n], 0, 0, 0);
    __syncthreads();
  }

  float bcol[2];
#pragma unroll
  for (int n = 0; n < 2; ++n) bcol[n] = bias[bx * 128 + w * 32 + n * 16 + lr];

#pragma unroll
  for (int m = 0; m < 4; ++m)
#pragma unroll
    for (int v = 0; v < 4; ++v) {
      const int r = m * 16 + lkq * 4 + v;
#pragma unroll
      for (int n = 0; n < 2; ++n)
        tileO[r][w * 32 + n * 16 + lr] = (bf16_t)(acc[m][n][v] + bcol[n]);
    }
  __syncthreads();

  // h store: 64 rows x 128 cols, coalesced
#pragma unroll
  for (int k = 0; k < 4; ++k) {
    const int idx = k * 256 + tid;
    const int row = idx >> 4, vec = idx & 15;
    bf16x8 vv = *(const bf16x8*)&tileO[row][vec * 8];
    *(bf16x8*)&h[(size_t)(by * 64 + row) * 512 + bx * 128 + vec * 8] = vv;
  }
  // hT store: 128 d-rows x 64 i, coalesced 128B segments
#pragma unroll
  for (int k = 0; k < 4; ++k) {
    const int idx = k * 256 + tid;
    const int d = idx >> 3, vec = idx & 7;
    bf16x8 u;
#pragma unroll
    for (int e = 0; e < 8; ++e) u[e] = tileO[vec * 8 + e][d];
    *(bf16x8*)&hT[(size_t)(bx * 128 + d) * 4096 + by * 64 + vec * 8] = u;
  }
}

// ================= 256x256 8-phase GEMM (T2+T3+T4+T5) =================
// EPI 1: out bf16 = exp(tanh(acc)), partial rowsums -> psum[(bx*4+wn)*4096+row]
// EPI 3: out bf16 = acc  (split-K partial at out + bz*pstride)
#define BAR() __builtin_amdgcn_s_barrier()
#define WLG() asm volatile("s_waitcnt lgkmcnt(0)" ::: "memory")
#define RDA(b, am)                                                              \
  do {                                                                          \
    _Pragma("unroll") for (int j = 0; j < 4; ++j) {                             \
      afr[j][0] = *(const bf16x8*)(pA + (b)*16384 + (am)*4096 + j*1024);        \
      afr[j][1] = *(const bf16x8*)(pA + (b)*16384 + 8192 + (am)*4096 + j*1024); \
    }                                                                           \
  } while (0)
#define RDB(b, bn)                                                              \
  do {                                                                          \
    _Pragma("unroll") for (int jj = 0; jj < 2; ++jj) {                          \
      bfr[jj][0] = *(const bf16x8*)(pB + (b)*16384 + ((bn)*2+jj)*1024);         \
      bfr[jj][1] = *(const bf16x8*)(pB + (b)*16384 + 8192 + ((bn)*2+jj)*1024);  \
    }                                                                           \
  } while (0)
#define MM16(am, bn)                                                            \
  do {                                                                          \
    __builtin_amdgcn_s_setprio(1);                                              \
    _Pragma("unroll") for (int kk = 0; kk < 2; ++kk)                            \
    _Pragma("unroll") for (int j = 0; j < 4; ++j)                               \
    _Pragma("unroll") for (int jj = 0; jj < 2; ++jj)                            \
      acc[(am)*4+j][(bn)*2+jj] = __builtin_amdgcn_mfma_f32_16x16x32_bf16(       \
          afr[j][kk], bfr[jj][kk], acc[(am)*4+j][(bn)*2+jj], 0, 0, 0);          \
    __builtin_amdgcn_s_setprio(0);                                              \
  } while (0)
#define STGA(tile, half)                                                        \
  do {                                                                          \
    const bf16_t* s_ = Ag + (size_t)(half)*128*lda + (tile)*64;                 \
    char* d_ = lds_raw + (half)*32768 + ((tile)&1)*16384 + tid*16;              \
    gload16(s_, d_); gload16(s_ + 32, d_ + 8192);                               \
  } while (0)
#define STGB(tile, half)                                                        \
  do {                                                                          \
    const bf16_t* s_ = Bg + (size_t)(half)*128*ldb + (tile)*64;                 \
    char* d_ = lds_raw + 65536 + (half)*32768 + ((tile)&1)*16384 + tid*16;      \
    gload16(s_, d_); gload16(s_ + 32, d_ + 8192);                               \
  } while (0)

template <int EPI>
__global__ __launch_bounds__(512, 2) void gemm8_k(const bf16_t* __restrict__ A,
                                                  const bf16_t* __restrict__ Bt,
                                                  bf16_t* __restrict__ out,
                                                  float* __restrict__ psum,
                                                  int lda, int ldb, int ldc,
                                                  int Klen, size_t pstride) {
  __shared__ __attribute__((aligned(16))) char lds_raw[131072];
  const int tid = threadIdx.x;
  const int wid = tid >> 6, l = tid & 63;
  const int wm = wid >> 2, wn = wid & 3;
  const int lr = l & 15, lkq = l >> 4;

  const int gx = gridDim.x, gy = gridDim.y;
  const int flat = blockIdx.x + gx * (blockIdx.y + gy * blockIdx.z);
  const int n = gx * gy * gridDim.z;
  const int s = (flat & 7) * (n >> 3) + (flat >> 3);
  const int lgx = __builtin_ctz(gx), lgy = __builtin_ctz(gy);
  const int bx = s & (gx - 1);
  const int by = (s >> lgx) & (gy - 1);
  const int bz = s >> (lgx + lgy);

  const size_t koff = (size_t)bz * Klen;
  const int NI = Klen >> 7;

  const int srow = tid >> 2;
  const int scol = ((tid & 3) * 8) ^ (((tid >> 5) & 1) << 4);
  const bf16_t* Ag = A + (size_t)(by * 256 + srow) * lda + koff + scol;
  const bf16_t* Bg = Bt + (size_t)(bx * 256 + srow) * ldb + koff + scol;

  const int kby = (lkq * 16) ^ (((lr >> 3) & 1) << 5);
  const char* pA = lds_raw + wm * 32768 + lr * 64 + kby;
  const char* pB = lds_raw + 65536 + (wn >> 1) * 32768 + ((wn & 1) * 64 + lr) * 64 + kby;

  bf16x8 afr[4][2], bfr[2][2];
  f32x4 acc[8][4];
#pragma unroll
  for (int m = 0; m < 8; ++m)
#pragma unroll
    for (int n2 = 0; n2 < 4; ++n2) acc[m][n2] = (f32x4){0.f, 0.f, 0.f, 0.f};

  STGA(0, 0); STGA(0, 1); STGB(0, 0); STGB(0, 1); STGA(1, 0);

  for (int i = 0; i < NI; ++i) {
    const int t1 = 2 * i + 1, t2 = 2 * i + 2, t3 = 2 * i + 3;
    const bool more = (i + 1 < NI);
    asm volatile("s_waitcnt vmcnt(2)" ::: "memory");
    BAR();
    RDA(0, 0); RDB(0, 0);
    STGA(t1, 1);
    WLG(); MM16(0, 0); BAR();
    RDB(0, 1); STGB(t1, 0);
    BAR(); WLG(); MM16(0, 1); BAR();
    RDA(0, 1); STGB(t1, 1);
    BAR(); WLG(); MM16(1, 1); BAR();
    RDB(0, 0);
    if (more) STGA(t2, 0);
    BAR(); WLG(); MM16(1, 0); BAR();
    if (more) { asm volatile("s_waitcnt vmcnt(2)" ::: "memory"); }
    else      { asm volatile("s_waitcnt vmcnt(0)" ::: "memory"); }
    BAR();
    RDA(1, 0); RDB(1, 0);
    if (more) STGA(t2, 1);
    WLG(); MM16(0, 0); BAR();
    RDB(1, 1);
    if (more) STGB(t2, 0);
    BAR(); WLG(); MM16(0, 1); BAR();
    RDA(1, 1);
    if (more) STGB(t2, 1);
    BAR(); WLG(); MM16(1, 1); BAR();
    RDB(1, 0);
    if (more) STGA(t3, 0);
    BAR(); WLG(); MM16(1, 0); BAR();
  }

  // epilogue: stash 256x256 bf16 tile into lds_raw, then coalesced store
  if constexpr (EPI == 1) {
    float* ps = psum + (size_t)(bx * 4 + wn) * 4096;
#pragma unroll
    for (int mi = 0; mi < 8; ++mi) {
#pragma unroll
      for (int v = 0; v < 4; ++v) {
        const int r = wm * 128 + mi * 16 + lkq * 4 + v;
        float rs = 0.f;
#pragma unroll
        for (int ni = 0; ni < 4; ++ni) {
          float val = __expf(tanh_fast(acc[mi][ni][v]));
          const int cb = ((wn * 64 + ni * 16 + lr) * 2) ^ ((r & 4) << 4);
          *(bf16_t*)(lds_raw + r * 512 + cb) = (bf16_t)val;
          rs += val;
        }
        rs += __shfl_xor(rs, 1);
        rs += __shfl_xor(rs, 2);
        rs += __shfl_xor(rs, 4);
        rs += __shfl_xor(rs, 8);
        if (lr == 0) ps[by * 256 + r] = rs;
      }
    }
  } else {
#pragma unroll
    for (int mi = 0; mi < 8; ++mi)
#pragma unroll
      for (int v = 0; v < 4; ++v) {
        const int r = wm * 128 + mi * 16 + lkq * 4 + v;
#pragma unroll
        for (int ni = 0; ni < 4; ++ni) {
          const int cb = ((wn * 64 + ni * 16 + lr) * 2) ^ ((r & 4) << 4);
          *(bf16_t*)(lds_raw + r * 512 + cb) = (bf16_t)acc[mi][ni][v];
        }
      }
  }
  __syncthreads();
  bf16_t* obase = (EPI == 1) ? out : out + (size_t)bz * pstride;
#pragma unroll
  for (int k = 0; k < 16; ++k) {
    const int idx = k * 512 + tid;
    const int row = idx >> 5, cc = idx & 31;
    bf16x8 vv = *(const bf16x8*)(lds_raw + ((row * 512 + cc * 16) ^ ((row & 4) << 4)));
    *(bf16x8*)&obase[(size_t)(by * 256 + row) * ldc + bx * 256 + cc * 8] = vv;
  }
}

// ---------------- 128x128 GEMM (fallback path only) ----------------
template <int EPI>
__global__ __launch_bounds__(256) void gemm_bt_k(const bf16_t* __restrict__ A,
                                                 const bf16_t* __restrict__ Bt,
                                                 const float* __restrict__ extra,
                                                 bf16_t* __restrict__ out,
                                                 float* __restrict__ outf,
                                                 float* __restrict__ psum,
                                                 int M, int N, int Kloop, int lda, int ldb) {
  __shared__ bf16_t As[128 * 32];
  __shared__ bf16_t Bs[128 * 32];
  const int tid = threadIdx.x;
  const int w = tid >> 6;
  const int l = tid & 63;
  const int bx = blockIdx.x, by = blockIdx.y;
  const int koff = blockIdx.z * Kloop;

  const bf16_t* src = (w < 2) ? A : Bt;
  const int stride = (w < 2) ? lda : ldb;
  bf16_t* dstbase = (w < 2) ? As : Bs;
  const int tile0 = (w < 2 ? by : bx) * 128 + (w & 1) * 64;
  const int srow = l >> 2;
  const int scol = (l & 3) * 8;
  const bf16_t* gbase = src + (size_t)(tile0 + srow) * stride + scol + koff;
  bf16_t* lbase = dstbase + (w & 1) * (64 * 32);

  const int wm = w >> 1, wn = w & 1;
  const int lrow = l & 15;
  const int lk = (l >> 4) * 8;

  f32x4 zero = {0.f, 0.f, 0.f, 0.f};
  f32x4 acc[4][4];
  for (int m = 0; m < 4; ++m)
    for (int n = 0; n < 4; ++n) acc[m][n] = zero;

  for (int kt = 0; kt < Kloop; kt += 32) {
    const bf16_t* g = gbase + kt;
#pragma unroll
    for (int i = 0; i < 4; ++i) gload16(g + (size_t)i * 16 * stride, lbase + i * 512);
    __syncthreads();
    bf16x8 af[4], bfv[4];
#pragma unroll
    for (int m = 0; m < 4; ++m)
      af[m] = *(const bf16x8*)&As[(wm * 64 + m * 16 + lrow) * 32 + lk];
#pragma unroll
    for (int n = 0; n < 4; ++n)
      bfv[n] = *(const bf16x8*)&Bs[(wn * 64 + n * 16 + lrow) * 32 + lk];
#pragma unroll
    for (int m = 0; m < 4; ++m)
#pragma unroll
      for (int n = 0; n < 4; ++n)
        acc[m][n] = __builtin_amdgcn_mfma_f32_16x16x32_bf16(af[m], bfv[n], acc[m][n], 0, 0, 0);
    __syncthreads();
  }

  const int row0 = by * 128 + wm * 64;
  const int col0 = bx * 128 + wn * 64;

  if constexpr (EPI == 3) {
    float* of = outf + (size_t)blockIdx.z * M * N;
#pragma unroll
    for (int m = 0; m < 4; ++m)
#pragma unroll
      for (int v = 0; v < 4; ++v) {
        const int row = row0 + m * 16 + ((l >> 4) << 2) + v;
#pragma unroll
        for (int n = 0; n < 4; ++n)
          of[(size_t)row * N + col0 + n * 16 + lrow] = acc[m][n][v];
      }
    return;
  }

  if constexpr (EPI == 1) {
#pragma unroll
    for (int m = 0; m < 4; ++m)
#pragma unroll
      for (int v = 0; v < 4; ++v) {
        const int row = row0 + m * 16 + ((l >> 4) << 2) + v;
        float rs = 0.f;
#pragma unroll
        for (int n = 0; n < 4; ++n) {
          const int col = col0 + n * 16 + lrow;
          float val = __expf(tanh_fast(acc[m][n][v]));
          out[(size_t)row * N + col] = (bf16_t)val;
          rs += val;
        }
        if (psum) {
          rs += __shfl_xor(rs, 1);
          rs += __shfl_xor(rs, 2);
          rs += __shfl_xor(rs, 4);
          rs += __shfl_xor(rs, 8);
          if ((l & 15) == 0) psum[(size_t)(bx * 2 + wn) * M + row] = rs;
        }
      }
    return;
  }

  float bcol[4];
#pragma unroll
  for (int n = 0; n < 4; ++n)
    bcol[n] = (EPI == 0) ? extra[col0 + n * 16 + lrow] : 0.f;

#pragma unroll
  for (int m = 0; m < 4; ++m) {
#pragma unroll
    for (int v = 0; v < 4; ++v) {
      const int row = row0 + m * 16 + ((l >> 4) << 2) + v;
      float inv_dn = 1.f;
      if constexpr (EPI == 2) inv_dn = 1.f / extra[row];
#pragma unroll
      for (int n = 0; n < 4; ++n) {
        const int col = col0 + n * 16 + lrow;
        float val = acc[m][n][v];
        float o;
        if constexpr (EPI == 0) o = val + bcol[n];
        else o = fmaxf(tanh_fast(val * inv_dn), 0.f);
        out[(size_t)row * N + col] = (bf16_t)o;
      }
    }
  }
}

// ---------------- fallback helpers (round-1 structure) ----------------
__global__ __launch_bounds__(256) void transpose_k(const bf16_t* __restrict__ h,
                                                   bf16_t* __restrict__ hT) {
  __shared__ bf16_t tile[64][65];
  const int i0 = blockIdx.x * 64;
  const int d0 = blockIdx.y * 64;
  const int tid = threadIdx.x;
#pragma unroll
  for (int p = 0; p < 2; ++p) {
    int r = p * 32 + (tid >> 3);
    int c8 = (tid & 7) * 8;
    bf16x8 v = *(const bf16x8*)&h[(size_t)(i0 + r) * 512 + d0 + c8];
#pragma unroll
    for (int k = 0; k < 8; ++k) tile[r][c8 + k] = v[k];
  }
  __syncthreads();
#pragma unroll
  for (int p = 0; p < 2; ++p) {
    int d = p * 32 + (tid >> 3);
    int i8 = (tid & 7) * 8;
    bf16x8 u;
#pragma unroll
    for (int k = 0; k < 8; ++k) u[k] = tile[i8 + k][d];
    *(bf16x8*)&hT[(size_t)(d0 + d) * 4096 + i0 + i8] = u;
  }
}

__global__ __launch_bounds__(256) void rowsum_k(const bf16_t* __restrict__ P,
                                                float* __restrict__ den) {
  const int r = blockIdx.x;
  const int tid = threadIdx.x;
  const bf16_t* p = P + (size_t)r * 4096 + tid * 16;
  bf16x8 a = *(const bf16x8*)p;
  bf16x8 b = *(const bf16x8*)(p + 8);
  float s = 0.f;
#pragma unroll
  for (int k = 0; k < 8; ++k) s += (float)a[k] + (float)b[k];
  __shared__ float red[256];
  red[tid] = s;
  __syncthreads();
  for (int off = 128; off > 0; off >>= 1) {
    if (tid < off) red[tid] += red[tid + off];
    __syncthreads();
  }
  if (tid == 0) den[r] = red[0];
}

// ==== fused conv (half-row blocks): partial reduce + den + tanh/relu + conv1 + conv2
__global__ __launch_bounds__(256, 4) void conv2_fused_k(const bf16_t* __restrict__ pg,
                                                        const float* __restrict__ psum,
                                                        const bf16_t* __restrict__ w2rg,
                                                        const float* __restrict__ w1,
                                                        const float* __restrict__ b1,
                                                        const float* __restrict__ b2,
                                                        float* __restrict__ out, int S) {
  __shared__ bf16_t trow[264];         // jl 0..259 <-> j = j0-2+jl
  __shared__ bf16_t z1t[258 * 40 + 8]; // m 0..257 <-> j' = j0-1+m, pad 40
  __shared__ bf16_t w2r[3072];         // [kk][o][c]
  __shared__ float w1s[96], b1s[32], b2s[32];
  __shared__ float den_s;
  const int r = blockIdx.x >> 1;
  const int half = blockIdx.x & 1;
  const int j0 = half * 256;
  const int tid = threadIdx.x;

  if (tid < 96) w1s[tid] = w1[tid];
  if (tid < 32) { b1s[tid] = b1[tid]; b2s[tid] = b2[tid]; }
  ((bf16x8*)w2r)[tid] = ((const bf16x8*)w2rg)[tid];
  if (tid < 128) ((bf16x8*)w2r)[256 + tid] = ((const bf16x8*)w2rg)[256 + tid];

  // den[r] = sum of 64 psum slots (wave 0)
  if (tid < 64) {
    float dp = psum[(size_t)tid * 4096 + r];
    dp += __shfl_xor(dp, 32);
    dp += __shfl_xor(dp, 16);
    dp += __shfl_xor(dp, 8);
    dp += __shfl_xor(dp, 4);
    dp += __shfl_xor(dp, 2);
    dp += __shfl_xor(dp, 1);
    if (tid == 0) den_s = dp;
  }

  // raw split-K sums for this block's t-window (j = j0-2+jl)
  float a0 = 0.f, a1 = 0.f;
  {
    const int jA = j0 - 2 + tid;
    if (jA >= 0 && jA < 512) {
      const bf16_t* pr = pg + (size_t)r * 512 + jA;
      for (int z = 0; z < S; ++z) a0 += (float)pr[(size_t)z * (4096 * 512)];
    }
    if (tid < 4) {
      const int jB = j0 - 2 + 256 + tid;
      if (jB >= 0 && jB < 512) {
        const bf16_t* pr = pg + (size_t)r * 512 + jB;
        for (int z = 0; z < S; ++z) a1 += (float)pr[(size_t)z * (4096 * 512)];
      }
    }
  }
  __syncthreads();  // den_s + w2r ready

  {
    const float inv = 1.f / den_s;
    const int jA = j0 - 2 + tid;
    trow[tid] = (jA >= 0 && jA < 512) ? (bf16_t)fmaxf(tanh_fast(a0 * inv), 0.f)
                                      : (bf16_t)0.f;
    if (tid < 4) {
      const int jB = j0 - 2 + 256 + tid;
      trow[256 + tid] = (jB >= 0 && jB < 512) ? (bf16_t)fmaxf(tanh_fast(a1 * inv), 0.f)
                                              : (bf16_t)0.f;
    }
  }
  __syncthreads();

  // conv1: z1t[m][c], m in [0,258), j' = j0-1+m; uses trow[m..m+2]
  {
    const int c = tid & 31;
    const int g = tid >> 5;
    const int mb = g * 33;
    const int me = (mb + 33 < 258) ? mb + 33 : 258;
    const float wc0 = w1s[c * 3], wc1 = w1s[c * 3 + 1], wc2 = w1s[c * 3 + 2];
    const float bb = b1s[c];
    float tm = (float)trow[mb];
    float t0 = (float)trow[mb + 1];
    for (int m = mb; m < me; ++m) {
      float tp2 = (float)trow[m + 2];
      float v = fmaxf(bb + wc0 * tm + wc1 * t0 + wc2 * tp2, 0.f);
      const int jp = j0 - 1 + m;
      if (jp < 0 || jp > 511) v = 0.f;
      z1t[m * 40 + c] = (bf16_t)v;
      tm = t0; t0 = tp2;
    }
  }
  __syncthreads();

  // conv2 as 3 shifted GEMMs over the 256-col window (4 waves x 64 cols)
  const int w = tid >> 6, l = tid & 63;
  const int lrow = l & 15;
  const int lk = (l >> 4) * 8;
  bf16x8 af[3][2];
#pragma unroll
  for (int kk = 0; kk < 3; ++kk)
#pragma unroll
    for (int m = 0; m < 2; ++m)
      af[kk][m] = *(const bf16x8*)&w2r[kk * 1024 + (m * 16 + lrow) * 32 + lk];

  f32x4 zero = {0.f, 0.f, 0.f, 0.f};
  f32x4 acc[2][4];
#pragma unroll
  for (int m = 0; m < 2; ++m)
#pragma unroll
    for (int n = 0; n < 4; ++n) acc[m][n] = zero;

  const int jlb = w * 64;
#pragma unroll
  for (int kk = 0; kk < 3; ++kk) {
#pragma unroll
    for (int n = 0; n < 4; ++n) {
      bf16x8 bfv = *(const bf16x8*)&z1t[(jlb + n * 16 + lrow + kk) * 40 + lk];
      acc[0][n] = __builtin_amdgcn_mfma_f32_16x16x32_bf16(af[kk][0], bfv, acc[0][n], 0, 0, 0);
      acc[1][n] = __builtin_amdgcn_mfma_f32_16x16x32_bf16(af[kk][1], bfv, acc[1][n], 0, 0, 0);
    }
  }

#pragma unroll
  for (int m = 0; m < 2; ++m) {
    const int ob = m * 16 + ((l >> 4) << 2);
    const float bb0 = b2s[ob], bb1 = b2s[ob + 1], bb2 = b2s[ob + 2], bb3 = b2s[ob + 3];
#pragma unroll
    for (int n = 0; n < 4; ++n) {
      const int j = j0 + jlb + n * 16 + lrow;
      f32x4 res;
      res[0] = fmaxf(acc[m][n][0] + bb0, 0.f);
      res[1] = fmaxf(acc[m][n][1] + bb1, 0.f);
      res[2] = fmaxf(acc[m][n][2] + bb2, 0.f);
      res[3] = fmaxf(acc[m][n][3] + bb3, 0.f);
      *(f32x4*)&out[((size_t)r * 512 + j) * 32 + ob] = res;
    }
  }
}

// ---------------- fallback conv (reads precomputed t row) ----------------
__global__ __launch_bounds__(256) void conv_fused_k(const bf16_t* __restrict__ t,
                                                    const float* __restrict__ w1,
                                                    const float* __restrict__ b1,
                                                    const float* __restrict__ w2,
                                                    const float* __restrict__ b2,
                                                    float* __restrict__ out) {
  __shared__ bf16_t trow[516];
  __shared__ bf16_t z1t[514 * 40];
  __shared__ bf16_t w2r[3 * 32 * 32];
  __shared__ float w1s[96], b1s[32], b2s[32];
  const int r = blockIdx.x;
  const int tid = threadIdx.x;

  if (tid < 96) w1s[tid] = w1[tid];
  if (tid < 32) { b1s[tid] = b1[tid]; b2s[tid] = b2[tid]; }
  for (int i = tid; i < 3072; i += 256) {
    int o = i / 96, rem = i % 96, c = rem / 3, kk = rem % 3;
    w2r[kk * 1024 + o * 32 + c] = (bf16_t)w2[i];
  }
  {
    const bf16_t* tp = t + (size_t)r * 512;
    trow[1 + tid] = tp[tid];
    trow[1 + 256 + tid] = tp[256 + tid];
    if (tid == 0) { trow[0] = (bf16_t)0.f; trow[513] = (bf16_t)0.f; }
    if (tid < 40) { z1t[tid] = (bf16_t)0.f; z1t[513 * 40 + tid] = (bf16_t)0.f; }
  }
  __syncthreads();

  {
    const int c = tid & 31;
    const int jb = (tid >> 5) * 64;
    const float wc0 = w1s[c * 3], wc1 = w1s[c * 3 + 1], wc2 = w1s[c * 3 + 2];
    const float bb = b1s[c];
    float tm = (float)trow[jb];
    float t0 = (float)trow[jb + 1];
    for (int j = jb; j < jb + 64; ++j) {
      float tp2 = (float)trow[j + 2];
      float v = fmaxf(bb + wc0 * tm + wc1 * t0 + wc2 * tp2, 0.f);
      z1t[(j + 1) * 40 + c] = (bf16_t)v;
      tm = t0; t0 = tp2;
    }
  }
  __syncthreads();

  const int w = tid >> 6, l = tid & 63;
  const int lrow = l & 15;
  const int lk = (l >> 4) * 8;
  bf16x8 af[3][2];
#pragma unroll
  for (int kk = 0; kk < 3; ++kk)
#pragma unroll
    for (int m = 0; m < 2; ++m)
      af[kk][m] = *(const bf16x8*)&w2r[kk * 1024 + (m * 16 + lrow) * 32 + lk];

  f32x4 zero = {0.f, 0.f, 0.f, 0.f};
  f32x4 acc[2][8];
#pragma unroll
  for (int m = 0; m < 2; ++m)
#pragma unroll
    for (int n = 0; n < 8; ++n) acc[m][n] = zero;

  const int j0 = w * 128;
#pragma unroll
  for (int kk = 0; kk < 3; ++kk) {
#pragma unroll
    for (int n = 0; n < 8; ++n) {
      bf16x8 bfv = *(const bf16x8*)&z1t[(j0 + n * 16 + lrow + kk) * 40 + lk];
      acc[0][n] = __builtin_amdgcn_mfma_f32_16x16x32_bf16(af[kk][0], bfv, acc[0][n], 0, 0, 0);
      acc[1][n] = __builtin_amdgcn_mfma_f32_16x16x32_bf16(af[kk][1], bfv, acc[1][n], 0, 0, 0);
    }
  }

#pragma unroll
  for (int m = 0; m < 2; ++m) {
    const int ob = m * 16 + ((l >> 4) << 2);
    const float bb0 = b2s[ob], bb1 = b2s[ob + 1], bb2 = b2s[ob + 2], bb3 = b2s[ob + 3];
#pragma unroll
    for (int n = 0; n < 8; ++n) {
      const int j = j0 + n * 16 + lrow;
      f32x4 res;
      res[0] = fmaxf(acc[m][n][0] + bb0, 0.f);
      res[1] = fmaxf(acc[m][n][1] + bb1, 0.f);
      res[2] = fmaxf(acc[m][n][2] + bb2, 0.f);
      res[3] = fmaxf(acc[m][n][3] + bb3, 0.f);
      *(f32x4*)&out[((size_t)r * 512 + j) * 32 + ob] = res;
    }
  }
}

// ---------------- launch ----------------
extern "C" void kernel_launch(void* const* d_in, const int* in_sizes, int n_in,
                              void* d_out, int out_size, void* d_ws, size_t ws_size,
                              hipStream_t stream) {
  const float* x = (const float*)d_in[0];
  const float* Ww = (const float*)d_in[1];
  const float* Wb = (const float*)d_in[2];
  const float* c1w = (const float*)d_in[3];
  const float* c1b = (const float*)d_in[4];
  const float* c2w = (const float*)d_in[5];
  const float* c2b = (const float*)d_in[6];
  float* out = (float*)d_out;
  char* ws = (char*)d_ws;

  bf16_t* xb  = (bf16_t*)(ws + 0);          //  8 MB (fallback only)
  bf16_t* Wbf = (bf16_t*)(ws + 8388608);    //  1 MB (512x1024)
  bf16_t* h   = (bf16_t*)(ws + 9437184);    //  4 MB (4096x512)
  bf16_t* hT  = (bf16_t*)(ws + 13631488);   //  4 MB (512x4096)
  bf16_t* tb  = (bf16_t*)(ws + 17825792);   //  4 MB (fallback only)
  bf16_t* w2rg = (bf16_t*)(ws + 17825792);  //  6 KB (fast path; aliases tb slot)
  float*  den = (float*)(ws + 22020096);    // 16 KB (fallback only)

  const size_t NEED_FAST = 73416704ull;  // psum + P + 16MB GEMM3 partials (S=4)
  if (ws_size >= NEED_FAST) {
    float*  psum = (float*)(ws + 22036480);    //  1 MB (64 x 4096)
    bf16_t* P    = (bf16_t*)(ws + 23085056);   // 32 MB (4096x4096)
    bf16_t* pg3b = (bf16_t*)(ws + 56639488);   // S x 4 MB bf16 GEMM3 partials

    cast_w_k<<<513, 256, 0, stream>>>(Ww, c2w, Wbf, w2rg);

    // h = x @ Ww^T + Wb  (x cast fused into staging; bias + h + hT epilogue)
    gemm1_fused_k<<<dim3(4, 64), 256, 0, stream>>>(x, Wbf, Wb, h, hT);

    // P = exp(tanh(h @ h^T)) + fused partial rowsums  (256^2 8-phase)
    gemm8_k<1><<<dim3(16, 16, 1), 512, 0, stream>>>(h, h, P, psum, 512, 512, 4096, 512, 0);

    // P @ h  (256^2 8-phase, split-K, bf16 partials)
    const int S = (ws_size >= 90193920ull) ? 8 : 4;
    gemm8_k<3><<<dim3(2, 16, S), 512, 0, stream>>>(P, hT, pg3b, nullptr, 4096, 4096, 512,
                                                   4096 / S, (size_t)4096 * 512);

    // fused: reduce partials + den + tanh/relu + conv1 + conv2 (half-row blocks)
    conv2_fused_k<<<8192, 256, 0, stream>>>(pg3b, psum, w2rg, c1w, c1b, c2b, out, S);
  } else {
    // fallback: round-1 structure, fits in 53 MB
    bf16_t* P = (bf16_t*)(ws + 22036480);
    cast_all_k<<<4609, 256, 0, stream>>>(x, Ww, c2w, xb, Wbf, w2rg);
    gemm_bt_k<0><<<dim3(4, 32), 256, 0, stream>>>(xb, Wbf, Wb, h, nullptr, nullptr,
                                                  4096, 512, 1024, 1024, 1024);
    transpose_k<<<dim3(64, 8), 256, 0, stream>>>(h, hT);
    gemm_bt_k<1><<<dim3(32, 32), 256, 0, stream>>>(h, h, nullptr, P, nullptr, nullptr,
                                                   4096, 4096, 512, 512, 512);
    rowsum_k<<<4096, 256, 0, stream>>>(P, den);
    gemm_bt_k<2><<<dim3(4, 32), 256, 0, stream>>>(P, hT, den, tb, nullptr, nullptr,
                                                  4096, 512, 4096, 4096, 4096);
    conv_fused_k<<<4096, 256, 0, stream>>>(tb, c1w, c1b, c2w, c2b, out);
  }
}

// Round 9
// 180.994 us; speedup vs baseline: 1.0410x; 1.0410x over previous
//
#include <hip/hip_runtime.h>

typedef __bf16 bf16_t;
typedef __bf16 bf16x8 __attribute__((ext_vector_type(8)));
typedef __bf16 bf16x4v __attribute__((ext_vector_type(4)));
typedef __bf16 bf16x2 __attribute__((ext_vector_type(2)));
typedef float f32x4 __attribute__((ext_vector_type(4)));

__device__ __forceinline__ float tanh_fast(float x) {
  float a = fabsf(x);
  float e = __expf(-2.f * a);
  float t = (1.f - e) * __builtin_amdgcn_rcpf(1.f + e);
  return copysignf(t, x);
}

__device__ __forceinline__ void gload16(const void* g, void* l) {
  __builtin_amdgcn_global_load_lds(
      (const __attribute__((address_space(1))) void*)g,
      (__attribute__((address_space(3))) void*)l, 16, 0, 0);
}

// ------- cast x -> bf16, W -> bf16, and pre-layout conv2 weights, one kernel
__global__ __launch_bounds__(256) void cast_all_k(const float* __restrict__ x,
                                                  const float* __restrict__ Ww,
                                                  const float* __restrict__ w2,
                                                  bf16_t* __restrict__ xb,
                                                  bf16_t* __restrict__ Wbf,
                                                  bf16_t* __restrict__ w2rg) {
  const int bid = blockIdx.x;
  const int tid = threadIdx.x;
  if (bid < 4096) {
    const int i = bid * 256 + tid;
    float4 v = ((const float4*)x)[i];
    bf16x4v o;
    o[0] = (bf16_t)v.x; o[1] = (bf16_t)v.y; o[2] = (bf16_t)v.z; o[3] = (bf16_t)v.w;
    ((bf16x4v*)xb)[i] = o;
  } else if (bid < 4608) {
    const int i = (bid - 4096) * 256 + tid;
    float4 v = ((const float4*)Ww)[i];
    bf16x4v o;
    o[0] = (bf16_t)v.x; o[1] = (bf16_t)v.y; o[2] = (bf16_t)v.z; o[3] = (bf16_t)v.w;
    ((bf16x4v*)Wbf)[i] = o;
  } else {
    for (int i = tid; i < 3072; i += 256) {
      int o = i / 96, rem = i % 96, c = rem / 3, kk = rem % 3;
      w2rg[kk * 1024 + o * 32 + c] = (bf16_t)w2[i];
    }
  }
}

// ===== fused GEMM1: h = x@W^T + b, also writes hT. 64x128 tile, grid (4,64) =====
__global__ __launch_bounds__(256) void gemm1_fused_k(const bf16_t* __restrict__ xb,
                                                     const bf16_t* __restrict__ Wbf,
                                                     const float* __restrict__ bias,
                                                     bf16_t* __restrict__ h,
                                                     bf16_t* __restrict__ hT) {
  __shared__ bf16_t As[64 * 32];
  __shared__ bf16_t Bs[128 * 32];
  __shared__ bf16_t tileO[64][136];  // padded: rows 272B (16B-aligned, bank-shifted)
  const int tid = threadIdx.x;
  const int w = tid >> 6, l = tid & 63;
  const int lr = l & 15, lkq = l >> 4;
  const int bx = blockIdx.x, by = blockIdx.y;

  const bf16_t* Ag  = xb + (size_t)(by * 64 + (tid >> 2)) * 1024 + (tid & 3) * 8;
  const bf16_t* Bg0 = Wbf + (size_t)(bx * 128 + (tid >> 2)) * 1024 + (tid & 3) * 8;
  const bf16_t* Bg1 = Bg0 + (size_t)64 * 1024;
  bf16_t* lA  = As + tid * 8;
  bf16_t* lB0 = Bs + tid * 8;
  bf16_t* lB1 = Bs + 2048 + tid * 8;

  f32x4 acc[4][2];
#pragma unroll
  for (int m = 0; m < 4; ++m)
#pragma unroll
    for (int n = 0; n < 2; ++n) acc[m][n] = (f32x4){0.f, 0.f, 0.f, 0.f};

  for (int kt = 0; kt < 1024; kt += 32) {
    gload16(Ag + kt, lA);
    gload16(Bg0 + kt, lB0);
    gload16(Bg1 + kt, lB1);
    __syncthreads();  // compiler drains vmcnt before s_barrier
    bf16x8 af[4], bfv[2];
#pragma unroll
    for (int m = 0; m < 4; ++m)
      af[m] = *(const bf16x8*)&As[(m * 16 + lr) * 32 + lkq * 8];
#pragma unroll
    for (int n = 0; n < 2; ++n)
      bfv[n] = *(const bf16x8*)&Bs[(w * 32 + n * 16 + lr) * 32 + lkq * 8];
#pragma unroll
    for (int m = 0; m < 4; ++m)
#pragma unroll
      for (int n = 0; n < 2; ++n)
        acc[m][n] = __builtin_amdgcn_mfma_f32_16x16x32_bf16(af[m], bfv[n], acc[m][n], 0, 0, 0);
    __syncthreads();
  }

  float bcol[2];
#pragma unroll
  for (int n = 0; n < 2; ++n) bcol[n] = bias[bx * 128 + w * 32 + n * 16 + lr];

#pragma unroll
  for (int m = 0; m < 4; ++m)
#pragma unroll
    for (int v = 0; v < 4; ++v) {
      const int r = m * 16 + lkq * 4 + v;
#pragma unroll
      for (int n = 0; n < 2; ++n)
        tileO[r][w * 32 + n * 16 + lr] = (bf16_t)(acc[m][n][v] + bcol[n]);
    }
  __syncthreads();

  // h store: 64 rows x 128 cols, coalesced
#pragma unroll
  for (int k = 0; k < 4; ++k) {
    const int idx = k * 256 + tid;
    const int row = idx >> 4, vec = idx & 15;
    bf16x8 vv = *(const bf16x8*)&tileO[row][vec * 8];
    *(bf16x8*)&h[(size_t)(by * 64 + row) * 512 + bx * 128 + vec * 8] = vv;
  }
  // hT store: 128 d-rows x 64 i, coalesced 128B segments
#pragma unroll
  for (int k = 0; k < 4; ++k) {
    const int idx = k * 256 + tid;
    const int d = idx >> 3, vec = idx & 7;
    bf16x8 u;
#pragma unroll
    for (int e = 0; e < 8; ++e) u[e] = tileO[vec * 8 + e][d];
    *(bf16x8*)&hT[(size_t)(bx * 128 + d) * 4096 + by * 64 + vec * 8] = u;
  }
}

// ================= 256x256 8-phase GEMM (T2+T3+T4+T5) =================
// EPI 1: out bf16 = exp(tanh(acc)), partial rowsums -> psum[(bx*4+wn)*4096+row]
// EPI 3: out bf16 = acc  (split-K partial at out + bz*pstride)
#define BAR() __builtin_amdgcn_s_barrier()
#define WLG() asm volatile("s_waitcnt lgkmcnt(0)" ::: "memory")
#define RDA(b, am)                                                              \
  do {                                                                          \
    _Pragma("unroll") for (int j = 0; j < 4; ++j) {                             \
      afr[j][0] = *(const bf16x8*)(pA + (b)*16384 + (am)*4096 + j*1024);        \
      afr[j][1] = *(const bf16x8*)(pA + (b)*16384 + 8192 + (am)*4096 + j*1024); \
    }                                                                           \
  } while (0)
#define RDB(b, bn)                                                              \
  do {                                                                          \
    _Pragma("unroll") for (int jj = 0; jj < 2; ++jj) {                          \
      bfr[jj][0] = *(const bf16x8*)(pB + (b)*16384 + ((bn)*2+jj)*1024);         \
      bfr[jj][1] = *(const bf16x8*)(pB + (b)*16384 + 8192 + ((bn)*2+jj)*1024);  \
    }                                                                           \
  } while (0)
#define MM16(am, bn)                                                            \
  do {                                                                          \
    __builtin_amdgcn_s_setprio(1);                                              \
    _Pragma("unroll") for (int kk = 0; kk < 2; ++kk)                            \
    _Pragma("unroll") for (int j = 0; j < 4; ++j)                               \
    _Pragma("unroll") for (int jj = 0; jj < 2; ++jj)                            \
      acc[(am)*4+j][(bn)*2+jj] = __builtin_amdgcn_mfma_f32_16x16x32_bf16(       \
          afr[j][kk], bfr[jj][kk], acc[(am)*4+j][(bn)*2+jj], 0, 0, 0);          \
    __builtin_amdgcn_s_setprio(0);                                              \
  } while (0)
#define STGA(tile, half)                                                        \
  do {                                                                          \
    const bf16_t* s_ = Ag + (size_t)(half)*128*lda + (tile)*64;                 \
    char* d_ = lds_raw + (half)*32768 + ((tile)&1)*16384 + tid*16;              \
    gload16(s_, d_); gload16(s_ + 32, d_ + 8192);                               \
  } while (0)
#define STGB(tile, half)                                                        \
  do {                                                                          \
    const bf16_t* s_ = Bg + (size_t)(half)*128*ldb + (tile)*64;                 \
    char* d_ = lds_raw + 65536 + (half)*32768 + ((tile)&1)*16384 + tid*16;      \
    gload16(s_, d_); gload16(s_ + 32, d_ + 8192);                               \
  } while (0)

template <int EPI>
__global__ __launch_bounds__(512, 2) void gemm8_k(const bf16_t* __restrict__ A,
                                                  const bf16_t* __restrict__ Bt,
                                                  bf16_t* __restrict__ out,
                                                  float* __restrict__ psum,
                                                  int lda, int ldb, int ldc,
                                                  int Klen, size_t pstride) {
  __shared__ __attribute__((aligned(16))) char lds_raw[131072];
  const int tid = threadIdx.x;
  const int wid = tid >> 6, l = tid & 63;
  const int wm = wid >> 2, wn = wid & 3;
  const int lr = l & 15, lkq = l >> 4;

  const int gx = gridDim.x, gy = gridDim.y;
  const int flat = blockIdx.x + gx * (blockIdx.y + gy * blockIdx.z);
  const int n = gx * gy * gridDim.z;
  const int s = (flat & 7) * (n >> 3) + (flat >> 3);
  const int lgx = __builtin_ctz(gx), lgy = __builtin_ctz(gy);
  const int bx = s & (gx - 1);
  const int by = (s >> lgx) & (gy - 1);
  const int bz = s >> (lgx + lgy);

  const size_t koff = (size_t)bz * Klen;
  const int NI = Klen >> 7;

  const int srow = tid >> 2;
  const int scol = ((tid & 3) * 8) ^ (((tid >> 5) & 1) << 4);
  const bf16_t* Ag = A + (size_t)(by * 256 + srow) * lda + koff + scol;
  const bf16_t* Bg = Bt + (size_t)(bx * 256 + srow) * ldb + koff + scol;

  const int kby = (lkq * 16) ^ (((lr >> 3) & 1) << 5);
  const char* pA = lds_raw + wm * 32768 + lr * 64 + kby;
  const char* pB = lds_raw + 65536 + (wn >> 1) * 32768 + ((wn & 1) * 64 + lr) * 64 + kby;

  bf16x8 afr[4][2], bfr[2][2];
  f32x4 acc[8][4];
#pragma unroll
  for (int m = 0; m < 8; ++m)
#pragma unroll
    for (int n2 = 0; n2 < 4; ++n2) acc[m][n2] = (f32x4){0.f, 0.f, 0.f, 0.f};

  STGA(0, 0); STGA(0, 1); STGB(0, 0); STGB(0, 1); STGA(1, 0);

  for (int i = 0; i < NI; ++i) {
    const int t1 = 2 * i + 1, t2 = 2 * i + 2, t3 = 2 * i + 3;
    const bool more = (i + 1 < NI);
    asm volatile("s_waitcnt vmcnt(2)" ::: "memory");
    BAR();
    RDA(0, 0); RDB(0, 0);
    STGA(t1, 1);
    WLG(); MM16(0, 0); BAR();
    RDB(0, 1); STGB(t1, 0);
    BAR(); WLG(); MM16(0, 1); BAR();
    RDA(0, 1); STGB(t1, 1);
    BAR(); WLG(); MM16(1, 1); BAR();
    RDB(0, 0);
    if (more) STGA(t2, 0);
    BAR(); WLG(); MM16(1, 0); BAR();
    if (more) { asm volatile("s_waitcnt vmcnt(2)" ::: "memory"); }
    else      { asm volatile("s_waitcnt vmcnt(0)" ::: "memory"); }
    BAR();
    RDA(1, 0); RDB(1, 0);
    if (more) STGA(t2, 1);
    WLG(); MM16(0, 0); BAR();
    RDB(1, 1);
    if (more) STGB(t2, 0);
    BAR(); WLG(); MM16(0, 1); BAR();
    RDA(1, 1);
    if (more) STGB(t2, 1);
    BAR(); WLG(); MM16(1, 1); BAR();
    RDB(1, 0);
    if (more) STGA(t3, 0);
    BAR(); WLG(); MM16(1, 0); BAR();
  }

  // epilogue: stash 256x256 bf16 tile into lds_raw, then coalesced store
  if constexpr (EPI == 1) {
    float* ps = psum + (size_t)(bx * 4 + wn) * 4096;
#pragma unroll
    for (int mi = 0; mi < 8; ++mi) {
#pragma unroll
      for (int v = 0; v < 4; ++v) {
        const int r = wm * 128 + mi * 16 + lkq * 4 + v;
        float rs = 0.f;
#pragma unroll
        for (int ni = 0; ni < 4; ++ni) {
          float val = __expf(tanh_fast(acc[mi][ni][v]));
          const int cb = ((wn * 64 + ni * 16 + lr) * 2) ^ ((r & 4) << 4);
          *(bf16_t*)(lds_raw + r * 512 + cb) = (bf16_t)val;
          rs += val;
        }
        rs += __shfl_xor(rs, 1);
        rs += __shfl_xor(rs, 2);
        rs += __shfl_xor(rs, 4);
        rs += __shfl_xor(rs, 8);
        if (lr == 0) ps[by * 256 + r] = rs;
      }
    }
  } else {
#pragma unroll
    for (int mi = 0; mi < 8; ++mi)
#pragma unroll
      for (int v = 0; v < 4; ++v) {
        const int r = wm * 128 + mi * 16 + lkq * 4 + v;
#pragma unroll
        for (int ni = 0; ni < 4; ++ni) {
          const int cb = ((wn * 64 + ni * 16 + lr) * 2) ^ ((r & 4) << 4);
          *(bf16_t*)(lds_raw + r * 512 + cb) = (bf16_t)acc[mi][ni][v];
        }
      }
  }
  __syncthreads();
  bf16_t* obase = (EPI == 1) ? out : out + (size_t)bz * pstride;
#pragma unroll
  for (int k = 0; k < 16; ++k) {
    const int idx = k * 512 + tid;
    const int row = idx >> 5, cc = idx & 31;
    bf16x8 vv = *(const bf16x8*)(lds_raw + ((row * 512 + cc * 16) ^ ((row & 4) << 4)));
    *(bf16x8*)&obase[(size_t)(by * 256 + row) * ldc + bx * 256 + cc * 8] = vv;
  }
}

// ---------------- 128x128 GEMM (fallback path only) ----------------
template <int EPI>
__global__ __launch_bounds__(256) void gemm_bt_k(const bf16_t* __restrict__ A,
                                                 const bf16_t* __restrict__ Bt,
                                                 const float* __restrict__ extra,
                                                 bf16_t* __restrict__ out,
                                                 float* __restrict__ outf,
                                                 float* __restrict__ psum,
                                                 int M, int N, int Kloop, int lda, int ldb) {
  __shared__ bf16_t As[128 * 32];
  __shared__ bf16_t Bs[128 * 32];
  const int tid = threadIdx.x;
  const int w = tid >> 6;
  const int l = tid & 63;
  const int bx = blockIdx.x, by = blockIdx.y;
  const int koff = blockIdx.z * Kloop;

  const bf16_t* src = (w < 2) ? A : Bt;
  const int stride = (w < 2) ? lda : ldb;
  bf16_t* dstbase = (w < 2) ? As : Bs;
  const int tile0 = (w < 2 ? by : bx) * 128 + (w & 1) * 64;
  const int srow = l >> 2;
  const int scol = (l & 3) * 8;
  const bf16_t* gbase = src + (size_t)(tile0 + srow) * stride + scol + koff;
  bf16_t* lbase = dstbase + (w & 1) * (64 * 32);

  const int wm = w >> 1, wn = w & 1;
  const int lrow = l & 15;
  const int lk = (l >> 4) * 8;

  f32x4 zero = {0.f, 0.f, 0.f, 0.f};
  f32x4 acc[4][4];
  for (int m = 0; m < 4; ++m)
    for (int n = 0; n < 4; ++n) acc[m][n] = zero;

  for (int kt = 0; kt < Kloop; kt += 32) {
    const bf16_t* g = gbase + kt;
#pragma unroll
    for (int i = 0; i < 4; ++i) gload16(g + (size_t)i * 16 * stride, lbase + i * 512);
    __syncthreads();
    bf16x8 af[4], bfv[4];
#pragma unroll
    for (int m = 0; m < 4; ++m)
      af[m] = *(const bf16x8*)&As[(wm * 64 + m * 16 + lrow) * 32 + lk];
#pragma unroll
    for (int n = 0; n < 4; ++n)
      bfv[n] = *(const bf16x8*)&Bs[(wn * 64 + n * 16 + lrow) * 32 + lk];
#pragma unroll
    for (int m = 0; m < 4; ++m)
#pragma unroll
      for (int n = 0; n < 4; ++n)
        acc[m][n] = __builtin_amdgcn_mfma_f32_16x16x32_bf16(af[m], bfv[n], acc[m][n], 0, 0, 0);
    __syncthreads();
  }

  const int row0 = by * 128 + wm * 64;
  const int col0 = bx * 128 + wn * 64;

  if constexpr (EPI == 3) {
    float* of = outf + (size_t)blockIdx.z * M * N;
#pragma unroll
    for (int m = 0; m < 4; ++m)
#pragma unroll
      for (int v = 0; v < 4; ++v) {
        const int row = row0 + m * 16 + ((l >> 4) << 2) + v;
#pragma unroll
        for (int n = 0; n < 4; ++n)
          of[(size_t)row * N + col0 + n * 16 + lrow] = acc[m][n][v];
      }
    return;
  }

  if constexpr (EPI == 1) {
#pragma unroll
    for (int m = 0; m < 4; ++m)
#pragma unroll
      for (int v = 0; v < 4; ++v) {
        const int row = row0 + m * 16 + ((l >> 4) << 2) + v;
        float rs = 0.f;
#pragma unroll
        for (int n = 0; n < 4; ++n) {
          const int col = col0 + n * 16 + lrow;
          float val = __expf(tanh_fast(acc[m][n][v]));
          out[(size_t)row * N + col] = (bf16_t)val;
          rs += val;
        }
        if (psum) {
          rs += __shfl_xor(rs, 1);
          rs += __shfl_xor(rs, 2);
          rs += __shfl_xor(rs, 4);
          rs += __shfl_xor(rs, 8);
          if ((l & 15) == 0) psum[(size_t)(bx * 2 + wn) * M + row] = rs;
        }
      }
    return;
  }

  float bcol[4];
#pragma unroll
  for (int n = 0; n < 4; ++n)
    bcol[n] = (EPI == 0) ? extra[col0 + n * 16 + lrow] : 0.f;

#pragma unroll
  for (int m = 0; m < 4; ++m) {
#pragma unroll
    for (int v = 0; v < 4; ++v) {
      const int row = row0 + m * 16 + ((l >> 4) << 2) + v;
      float inv_dn = 1.f;
      if constexpr (EPI == 2) inv_dn = 1.f / extra[row];
#pragma unroll
      for (int n = 0; n < 4; ++n) {
        const int col = col0 + n * 16 + lrow;
        float val = acc[m][n][v];
        float o;
        if constexpr (EPI == 0) o = val + bcol[n];
        else o = fmaxf(tanh_fast(val * inv_dn), 0.f);
        out[(size_t)row * N + col] = (bf16_t)o;
      }
    }
  }
}

// ---------------- fallback helpers (round-1 structure) ----------------
__global__ __launch_bounds__(256) void transpose_k(const bf16_t* __restrict__ h,
                                                   bf16_t* __restrict__ hT) {
  __shared__ bf16_t tile[64][65];
  const int i0 = blockIdx.x * 64;
  const int d0 = blockIdx.y * 64;
  const int tid = threadIdx.x;
#pragma unroll
  for (int p = 0; p < 2; ++p) {
    int r = p * 32 + (tid >> 3);
    int c8 = (tid & 7) * 8;
    bf16x8 v = *(const bf16x8*)&h[(size_t)(i0 + r) * 512 + d0 + c8];
#pragma unroll
    for (int k = 0; k < 8; ++k) tile[r][c8 + k] = v[k];
  }
  __syncthreads();
#pragma unroll
  for (int p = 0; p < 2; ++p) {
    int d = p * 32 + (tid >> 3);
    int i8 = (tid & 7) * 8;
    bf16x8 u;
#pragma unroll
    for (int k = 0; k < 8; ++k) u[k] = tile[i8 + k][d];
    *(bf16x8*)&hT[(size_t)(d0 + d) * 4096 + i0 + i8] = u;
  }
}

__global__ __launch_bounds__(256) void rowsum_k(const bf16_t* __restrict__ P,
                                                float* __restrict__ den) {
  const int r = blockIdx.x;
  const int tid = threadIdx.x;
  const bf16_t* p = P + (size_t)r * 4096 + tid * 16;
  bf16x8 a = *(const bf16x8*)p;
  bf16x8 b = *(const bf16x8*)(p + 8);
  float s = 0.f;
#pragma unroll
  for (int k = 0; k < 8; ++k) s += (float)a[k] + (float)b[k];
  __shared__ float red[256];
  red[tid] = s;
  __syncthreads();
  for (int off = 128; off > 0; off >>= 1) {
    if (tid < off) red[tid] += red[tid + off];
    __syncthreads();
  }
  if (tid == 0) den[r] = red[0];
}

// ==== fused: GEMM3-partial reduce + den reduce + tanh/relu + conv1 + conv2 ====
__global__ __launch_bounds__(256) void conv2_fused_k(const bf16_t* __restrict__ pg,
                                                     const float* __restrict__ psum,
                                                     const bf16_t* __restrict__ w2rg,
                                                     const float* __restrict__ w1,
                                                     const float* __restrict__ b1,
                                                     const float* __restrict__ b2,
                                                     float* __restrict__ out, int S) {
  __shared__ bf16_t trow[516];          // [0..513], halo at 0 and 513
  __shared__ bf16_t z1t[514 * 40];      // [j+1][c], rows padded to 40
  __shared__ bf16_t w2r[3072];          // [kk][o][c]
  __shared__ float w1s[96], b1s[32], b2s[32];
  __shared__ float den_s;
  const int r = blockIdx.x;
  const int tid = threadIdx.x;

  if (tid < 96) w1s[tid] = w1[tid];
  if (tid < 32) { b1s[tid] = b1[tid]; b2s[tid] = b2[tid]; }
  ((bf16x8*)w2r)[tid] = ((const bf16x8*)w2rg)[tid];
  if (tid < 128) ((bf16x8*)w2r)[256 + tid] = ((const bf16x8*)w2rg)[256 + tid];

  // den[r] = sum of 64 psum slots (wave 0)
  if (tid < 64) {
    float dp = psum[(size_t)tid * 4096 + r];
    dp += __shfl_xor(dp, 32);
    dp += __shfl_xor(dp, 16);
    dp += __shfl_xor(dp, 8);
    dp += __shfl_xor(dp, 4);
    dp += __shfl_xor(dp, 2);
    dp += __shfl_xor(dp, 1);
    if (tid == 0) den_s = dp;
  }

  // split-K partial sum for this row: thread tid handles j = 2*tid, 2*tid+1
  float a0 = 0.f, a1 = 0.f;
  {
    const bf16_t* pr = pg + (size_t)r * 512 + tid * 2;
    for (int z = 0; z < S; ++z) {
      bf16x2 v = *(const bf16x2*)(pr + (size_t)z * (4096 * 512));
      a0 += (float)v[0];
      a1 += (float)v[1];
    }
  }
  if (tid == 0) { trow[0] = (bf16_t)0.f; trow[513] = (bf16_t)0.f; }
  if (tid < 40) { z1t[tid] = (bf16_t)0.f; z1t[513 * 40 + tid] = (bf16_t)0.f; }
  __syncthreads();  // den_s + w2r ready

  {
    const float inv = 1.f / den_s;
    trow[1 + 2 * tid] = (bf16_t)fmaxf(tanh_fast(a0 * inv), 0.f);
    trow[2 + 2 * tid] = (bf16_t)fmaxf(tanh_fast(a1 * inv), 0.f);
  }
  __syncthreads();

  // conv1: z1t[j+1][c] = relu(b1[c] + sum_kk w1[c][kk] * t[j+kk-1])
  {
    const int c = tid & 31;
    const int jb = (tid >> 5) * 64;
    const float wc0 = w1s[c * 3], wc1 = w1s[c * 3 + 1], wc2 = w1s[c * 3 + 2];
    const float bb = b1s[c];
    float tm = (float)trow[jb];
    float t0 = (float)trow[jb + 1];
    for (int j = jb; j < jb + 64; ++j) {
      float tp2 = (float)trow[j + 2];
      float v = fmaxf(bb + wc0 * tm + wc1 * t0 + wc2 * tp2, 0.f);
      z1t[(j + 1) * 40 + c] = (bf16_t)v;
      tm = t0; t0 = tp2;
    }
  }
  __syncthreads();

  // conv2 as 3 shifted GEMMs
  const int w = tid >> 6, l = tid & 63;
  const int lrow = l & 15;
  const int lk = (l >> 4) * 8;
  bf16x8 af[3][2];
#pragma unroll
  for (int kk = 0; kk < 3; ++kk)
#pragma unroll
    for (int m = 0; m < 2; ++m)
      af[kk][m] = *(const bf16x8*)&w2r[kk * 1024 + (m * 16 + lrow) * 32 + lk];

  f32x4 zero = {0.f, 0.f, 0.f, 0.f};
  f32x4 acc[2][8];
#pragma unroll
  for (int m = 0; m < 2; ++m)
#pragma unroll
    for (int n = 0; n < 8; ++n) acc[m][n] = zero;

  const int j0 = w * 128;
#pragma unroll
  for (int kk = 0; kk < 3; ++kk) {
#pragma unroll
    for (int n = 0; n < 8; ++n) {
      bf16x8 bfv = *(const bf16x8*)&z1t[(j0 + n * 16 + lrow + kk) * 40 + lk];
      acc[0][n] = __builtin_amdgcn_mfma_f32_16x16x32_bf16(af[kk][0], bfv, acc[0][n], 0, 0, 0);
      acc[1][n] = __builtin_amdgcn_mfma_f32_16x16x32_bf16(af[kk][1], bfv, acc[1][n], 0, 0, 0);
    }
  }

#pragma unroll
  for (int m = 0; m < 2; ++m) {
    const int ob = m * 16 + ((l >> 4) << 2);
    const float bb0 = b2s[ob], bb1 = b2s[ob + 1], bb2 = b2s[ob + 2], bb3 = b2s[ob + 3];
#pragma unroll
    for (int n = 0; n < 8; ++n) {
      const int j = j0 + n * 16 + lrow;
      f32x4 res;
      res[0] = fmaxf(acc[m][n][0] + bb0, 0.f);
      res[1] = fmaxf(acc[m][n][1] + bb1, 0.f);
      res[2] = fmaxf(acc[m][n][2] + bb2, 0.f);
      res[3] = fmaxf(acc[m][n][3] + bb3, 0.f);
      *(f32x4*)&out[((size_t)r * 512 + j) * 32 + ob] = res;
    }
  }
}

// ---------------- fallback conv (reads precomputed t row) ----------------
__global__ __launch_bounds__(256) void conv_fused_k(const bf16_t* __restrict__ t,
                                                    const float* __restrict__ w1,
                                                    const float* __restrict__ b1,
                                                    const float* __restrict__ w2,
                                                    const float* __restrict__ b2,
                                                    float* __restrict__ out) {
  __shared__ bf16_t trow[516];
  __shared__ bf16_t z1t[514 * 40];
  __shared__ bf16_t w2r[3 * 32 * 32];
  __shared__ float w1s[96], b1s[32], b2s[32];
  const int r = blockIdx.x;
  const int tid = threadIdx.x;

  if (tid < 96) w1s[tid] = w1[tid];
  if (tid < 32) { b1s[tid] = b1[tid]; b2s[tid] = b2[tid]; }
  for (int i = tid; i < 3072; i += 256) {
    int o = i / 96, rem = i % 96, c = rem / 3, kk = rem % 3;
    w2r[kk * 1024 + o * 32 + c] = (bf16_t)w2[i];
  }
  {
    const bf16_t* tp = t + (size_t)r * 512;
    trow[1 + tid] = tp[tid];
    trow[1 + 256 + tid] = tp[256 + tid];
    if (tid == 0) { trow[0] = (bf16_t)0.f; trow[513] = (bf16_t)0.f; }
    if (tid < 40) { z1t[tid] = (bf16_t)0.f; z1t[513 * 40 + tid] = (bf16_t)0.f; }
  }
  __syncthreads();

  {
    const int c = tid & 31;
    const int jb = (tid >> 5) * 64;
    const float wc0 = w1s[c * 3], wc1 = w1s[c * 3 + 1], wc2 = w1s[c * 3 + 2];
    const float bb = b1s[c];
    float tm = (float)trow[jb];
    float t0 = (float)trow[jb + 1];
    for (int j = jb; j < jb + 64; ++j) {
      float tp2 = (float)trow[j + 2];
      float v = fmaxf(bb + wc0 * tm + wc1 * t0 + wc2 * tp2, 0.f);
      z1t[(j + 1) * 40 + c] = (bf16_t)v;
      tm = t0; t0 = tp2;
    }
  }
  __syncthreads();

  const int w = tid >> 6, l = tid & 63;
  const int lrow = l & 15;
  const int lk = (l >> 4) * 8;
  bf16x8 af[3][2];
#pragma unroll
  for (int kk = 0; kk < 3; ++kk)
#pragma unroll
    for (int m = 0; m < 2; ++m)
      af[kk][m] = *(const bf16x8*)&w2r[kk * 1024 + (m * 16 + lrow) * 32 + lk];

  f32x4 zero = {0.f, 0.f, 0.f, 0.f};
  f32x4 acc[2][8];
#pragma unroll
  for (int m = 0; m < 2; ++m)
#pragma unroll
    for (int n = 0; n < 8; ++n) acc[m][n] = zero;

  const int j0 = w * 128;
#pragma unroll
  for (int kk = 0; kk < 3; ++kk) {
#pragma unroll
    for (int n = 0; n < 8; ++n) {
      bf16x8 bfv = *(const bf16x8*)&z1t[(j0 + n * 16 + lrow + kk) * 40 + lk];
      acc[0][n] = __builtin_amdgcn_mfma_f32_16x16x32_bf16(af[kk][0], bfv, acc[0][n], 0, 0, 0);
      acc[1][n] = __builtin_amdgcn_mfma_f32_16x16x32_bf16(af[kk][1], bfv, acc[1][n], 0, 0, 0);
    }
  }

#pragma unroll
  for (int m = 0; m < 2; ++m) {
    const int ob = m * 16 + ((l >> 4) << 2);
    const float bb0 = b2s[ob], bb1 = b2s[ob + 1], bb2 = b2s[ob + 2], bb3 = b2s[ob + 3];
#pragma unroll
    for (int n = 0; n < 8; ++n) {
      const int j = j0 + n * 16 + lrow;
      f32x4 res;
      res[0] = fmaxf(acc[m][n][0] + bb0, 0.f);
      res[1] = fmaxf(acc[m][n][1] + bb1, 0.f);
      res[2] = fmaxf(acc[m][n][2] + bb2, 0.f);
      res[3] = fmaxf(acc[m][n][3] + bb3, 0.f);
      *(f32x4*)&out[((size_t)r * 512 + j) * 32 + ob] = res;
    }
  }
}

// ---------------- launch ----------------
extern "C" void kernel_launch(void* const* d_in, const int* in_sizes, int n_in,
                              void* d_out, int out_size, void* d_ws, size_t ws_size,
                              hipStream_t stream) {
  const float* x = (const float*)d_in[0];
  const float* Ww = (const float*)d_in[1];
  const float* Wb = (const float*)d_in[2];
  const float* c1w = (const float*)d_in[3];
  const float* c1b = (const float*)d_in[4];
  const float* c2w = (const float*)d_in[5];
  const float* c2b = (const float*)d_in[6];
  float* out = (float*)d_out;
  char* ws = (char*)d_ws;

  bf16_t* xb  = (bf16_t*)(ws + 0);          //  8 MB (4096x1024)
  bf16_t* Wbf = (bf16_t*)(ws + 8388608);    //  1 MB (512x1024)
  bf16_t* h   = (bf16_t*)(ws + 9437184);    //  4 MB (4096x512)
  bf16_t* hT  = (bf16_t*)(ws + 13631488);   //  4 MB (512x4096)
  bf16_t* tb  = (bf16_t*)(ws + 17825792);   //  4 MB (fallback only)
  bf16_t* w2rg = (bf16_t*)(ws + 17825792);  //  6 KB (fast path; aliases tb slot)
  float*  den = (float*)(ws + 22020096);    // 16 KB (fallback only)

  cast_all_k<<<4609, 256, 0, stream>>>(x, Ww, c2w, xb, Wbf, w2rg);

  const size_t NEED_FAST = 73416704ull;  // psum + P + 16MB GEMM3 partials (S=4)
  if (ws_size >= NEED_FAST) {
    float*  psum = (float*)(ws + 22036480);    //  1 MB (64 x 4096)
    bf16_t* P    = (bf16_t*)(ws + 23085056);   // 32 MB (4096x4096)
    bf16_t* pg3b = (bf16_t*)(ws + 56639488);   // S x 4 MB bf16 GEMM3 partials

    // h = x @ Ww^T + Wb  (fused: bias + h + hT, full occupancy, no split-K)
    gemm1_fused_k<<<dim3(4, 64), 256, 0, stream>>>(xb, Wbf, Wb, h, hT);

    // P = exp(tanh(h @ h^T)) + fused partial rowsums  (256^2 8-phase)
    gemm8_k<1><<<dim3(16, 16, 1), 512, 0, stream>>>(h, h, P, psum, 512, 512, 4096, 512, 0);

    // P @ h  (256^2 8-phase, split-K, bf16 partials)
    const int S = (ws_size >= 90193920ull) ? 8 : 4;
    gemm8_k<3><<<dim3(2, 16, S), 512, 0, stream>>>(P, hT, pg3b, nullptr, 4096, 4096, 512,
                                                   4096 / S, (size_t)4096 * 512);

    // fused: reduce partials + den + tanh/relu + conv1 + conv2 + transpose-out
    conv2_fused_k<<<4096, 256, 0, stream>>>(pg3b, psum, w2rg, c1w, c1b, c2b, out, S);
  } else {
    // fallback: round-1 structure, fits in 53 MB
    bf16_t* P = (bf16_t*)(ws + 22036480);
    gemm_bt_k<0><<<dim3(4, 32), 256, 0, stream>>>(xb, Wbf, Wb, h, nullptr, nullptr,
                                                  4096, 512, 1024, 1024, 1024);
    transpose_k<<<dim3(64, 8), 256, 0, stream>>>(h, hT);
    gemm_bt_k<1><<<dim3(32, 32), 256, 0, stream>>>(h, h, nullptr, P, nullptr, nullptr,
                                                   4096, 4096, 512, 512, 512);
    rowsum_k<<<4096, 256, 0, stream>>>(P, den);
    gemm_bt_k<2><<<dim3(4, 32), 256, 0, stream>>>(P, hT, den, tb, nullptr, nullptr,
                                                  4096, 512, 4096, 4096, 4096);
    conv_fused_k<<<4096, 256, 0, stream>>>(tb, c1w, c1b, c2w, c2b, out);
  }
}